// Round 8
// baseline (745.627 us; speedup 1.0000x reference)
//
#include <hip/hip_runtime.h>

typedef unsigned int u32;
typedef unsigned long long u64;
typedef double f64x4 __attribute__((ext_vector_type(4)));

#define NHEAD 8
#define NTOK 65536
#define DIM 128
#define MBLK 1024
#define KKEEP 52

// ---------------- coarsen: pick max-L2 token per 64-token block ----------------
__global__ __launch_bounds__(256) void coarsen_kernel(const float* __restrict__ x,
                                                      float* __restrict__ xc) {
    int b = blockIdx.x;              // 0..8191  (h * 1024 + mb)
    int h = b >> 10, mb = b & 1023;
    const float4* b4 = (const float4*)(x + ((size_t)h * NTOK + (size_t)mb * 64) * DIM);
    int tid = threadIdx.x;

    __shared__ double norms[64];
    __shared__ int best;

    #pragma unroll
    for (int u = 0; u < 8; ++u) {
        int f = tid + u * 256;               // f>>5 = token, f&31 = lane's f4 within token
        float4 v = b4[f];
        double s = (double)v.x * v.x + (double)v.y * v.y + (double)v.z * v.z + (double)v.w * v.w;
        #pragma unroll
        for (int off = 1; off < 32; off <<= 1) s += __shfl_xor(s, off);
        if ((tid & 31) == 0) norms[f >> 5] = s;
    }
    __syncthreads();

    if (tid < 64) {   // wave 0: argmax with first-index tie-break
        double v = norms[tid]; int idx = tid;
        #pragma unroll
        for (int off = 32; off; off >>= 1) {
            double ov = __shfl_down(v, off);
            int oi = __shfl_down(idx, off);
            if (ov > v || (ov == v && oi < idx)) { v = ov; idx = oi; }
        }
        if (tid == 0) best = idx;
    }
    __syncthreads();

    if (tid < 32) {
        float4* dst = (float4*)(xc + ((size_t)h * MBLK + mb) * DIM);
        dst[tid] = b4[best * 32 + tid];
    }
}

// ---------------- affinity: A[h] = relu(qc kc^T * scale), fp64 out ----------------
__global__ __launch_bounds__(256) void affinity_kernel(const float* __restrict__ qc,
                                                       const float* __restrict__ kc,
                                                       double* __restrict__ A) {
    __shared__ double qs[32][70];   // [d][i], padded
    __shared__ double ks[32][70];   // [d][j]
    int b = blockIdx.x;             // 8 * 16 * 16 = 2048
    int h = b >> 8, ti = (b >> 4) & 15, tj = b & 15;
    int i0 = ti * 64, j0 = tj * 64;
    int tid = threadIdx.x, tx = tid & 15, ty = tid >> 4;

    double acc[4][4] = {};
    const float4* qg = (const float4*)(qc + ((size_t)h * MBLK + i0) * DIM);
    const float4* kg = (const float4*)(kc + ((size_t)h * MBLK + j0) * DIM);

    for (int dk = 0; dk < 4; ++dk) {        // K=128 in chunks of 32
        __syncthreads();
        #pragma unroll
        for (int u = 0; u < 2; ++u) {
            int f = tid + u * 256;          // 0..511 ; row = f>>3, dp = f&7
            int row = f >> 3, dp = f & 7;
            float4 qv = qg[row * 32 + dk * 8 + dp];
            float4 kv = kg[row * 32 + dk * 8 + dp];
            int d0 = dp * 4;
            qs[d0 + 0][row] = qv.x; qs[d0 + 1][row] = qv.y;
            qs[d0 + 2][row] = qv.z; qs[d0 + 3][row] = qv.w;
            ks[d0 + 0][row] = kv.x; ks[d0 + 1][row] = kv.y;
            ks[d0 + 2][row] = kv.z; ks[d0 + 3][row] = kv.w;
        }
        __syncthreads();
        #pragma unroll
        for (int d = 0; d < 32; ++d) {
            double a[4], bb[4];
            *(double2*)&a[0]  = *(const double2*)&qs[d][ty * 2];
            *(double2*)&a[2]  = *(const double2*)&qs[d][32 + ty * 2];
            *(double2*)&bb[0] = *(const double2*)&ks[d][tx * 2];
            *(double2*)&bb[2] = *(const double2*)&ks[d][32 + tx * 2];
            #pragma unroll
            for (int r = 0; r < 4; ++r)
                #pragma unroll
                for (int c = 0; c < 4; ++c)
                    acc[r][c] += a[r] * bb[c];
        }
    }

    const double scale = 1.0 / sqrt(128.0);   // IEEE-exact, matches python
    #pragma unroll
    for (int r = 0; r < 4; ++r) {
        int i = i0 + (r >> 1) * 32 + ty * 2 + (r & 1);
        #pragma unroll
        for (int c = 0; c < 4; c += 2) {
            int j = j0 + (c >> 1) * 32 + tx * 2;
            double2 v;
            double v0 = acc[r][c]     * scale; if (v0 < 0.0) v0 = 0.0;
            double v1 = acc[r][c + 1] * scale; if (v1 < 0.0) v1 = 0.0;
            v.x = v0; v.y = v1;
            *(double2*)&A[((size_t)h << 20) + ((size_t)i << 10) + j] = v;
        }
    }
}

// ---------------- degrees ----------------
__global__ __launch_bounds__(256) void degout_kernel(const double* __restrict__ A,
                                                     double* __restrict__ dout) {
    int r = blockIdx.x * 4 + (threadIdx.x >> 6);   // 8192 rows, grid 2048
    int lane = threadIdx.x & 63;
    const double* row = A + ((size_t)r << 10);
    double s = 0.0;
    #pragma unroll
    for (int it = 0; it < 16; ++it) s += row[lane + it * 64];
    #pragma unroll
    for (int off = 1; off < 64; off <<= 1) s += __shfl_xor(s, off);
    if (lane == 0) dout[r] = s;
}

__global__ __launch_bounds__(256) void degin_kernel(const double* __restrict__ A,
                                                    double* __restrict__ din) {
    int b = blockIdx.x;           // 8 heads * 16 colgroups = 128
    int h = b >> 4, cg = b & 15;
    int tid = threadIdx.x;
    int col = cg * 64 + (tid & 63);
    int rc = tid >> 6;            // 0..3, each sums 256 rows
    const double* base = A + ((size_t)h << 20) + col;
    double s = 0.0;
    for (int i = rc * 256; i < rc * 256 + 256; ++i) s += base[(size_t)i << 10];
    __shared__ double part[4][64];
    part[rc][tid & 63] = s;
    __syncthreads();
    if (tid < 64) din[h * MBLK + cg * 64 + tid] = part[0][tid] + part[1][tid] + part[2][tid] + part[3][tid];
}

// ---------------- triangles + neg_frc via fp64 MFMA, 64x64 tile / many-block overlap ----
// Tile 64x64, BK=16, 256 threads (4 waves, each wave = 16 rows x 64 cols, acc = 4 f64x4).
// Grid 2048 blocks -> up to ~6-7 waves/SIMD, each from a DIFFERENT block at an
// independent k-phase: staging/barriers of one block hide under others' MFMAs.
// A frag: row=lane&15, k=lane>>4 ; B frag: col=lane&15, k=lane>>4.
// C/D layout measured at runtime via 4-MFMA probe (exact-integer D = i*16+j).
__global__ __launch_bounds__(256, 6) void tri_kernel(const double* __restrict__ A,
                                                     const double* __restrict__ dout,
                                                     const double* __restrict__ din,
                                                     double* __restrict__ neg) {
    __shared__ double asub[16][68];   // [k][i]
    __shared__ double bsub[16][68];   // [k][j]
    int h = blockIdx.z, ti = blockIdx.y, tj = blockIdx.x;
    int i0 = ti * 64, j0 = tj * 64;
    int tid = threadIdx.x;
    int wv = tid >> 6, lane = tid & 63;
    int lr = lane & 15, lk = lane >> 4;

    // ---- layout probe: D[i][j] = i*16 + j ----
    f64x4 probe = {0.0, 0.0, 0.0, 0.0};
    #pragma unroll
    for (int t = 0; t < 4; ++t) {
        double pa = (lr == 4 * t + lk) ? 1.0 : 0.0;        // A[i][k] = (i == 4t+k)
        double pb = (double)((4 * t + lk) * 16 + lr);      // B[k][j] = (4t+k)*16 + j
        probe = __builtin_amdgcn_mfma_f64_16x16x4f64(pa, pb, probe, 0, 0, 0);
    }
    int prow[4], pcol[4];
    #pragma unroll
    for (int g = 0; g < 4; ++g) {
        int v = (int)probe[g];
        prow[g] = v >> 4;
        pcol[g] = v & 15;
    }

    f64x4 acc[4];
    #pragma unroll
    for (int c = 0; c < 4; ++c) {
        f64x4 z = {0.0, 0.0, 0.0, 0.0};
        acc[c] = z;
    }

    const double* Ah = A + ((size_t)h << 20);

    // staging coords: u=0..1, f = tid + u*256 in [0,512)
    //   A tile 64 rows x 8 double2 (k): arow = f>>3, akp = f&7
    //   B tile 16 k-rows x 32 double2 (j): bkr = f>>5, bc2 = f&31
    int arow[2], akp[2], bkr[2], bc2[2];
    #pragma unroll
    for (int u = 0; u < 2; ++u) {
        int f = tid + u * 256;
        arow[u] = f >> 3;  akp[u] = f & 7;
        bkr[u]  = f >> 5;  bc2[u] = f & 31;
    }

    for (int kt = 0; kt < 1024; kt += 16) {
        __syncthreads();
        #pragma unroll
        for (int u = 0; u < 2; ++u) {          // A tile 64x16 (transposed store)
            double2 v = *(const double2*)&Ah[((size_t)(i0 + arow[u]) << 10) + kt + akp[u] * 2];
            asub[akp[u] * 2][arow[u]] = v.x;
            asub[akp[u] * 2 + 1][arow[u]] = v.y;
        }
        #pragma unroll
        for (int u = 0; u < 2; ++u) {          // B tile 16x64 (direct)
            double2 v = *(const double2*)&Ah[((size_t)(kt + bkr[u]) << 10) + j0 + bc2[u] * 2];
            *(double2*)&bsub[bkr[u]][bc2[u] * 2] = v;
        }
        __syncthreads();
        #pragma unroll
        for (int ks = 0; ks < 4; ++ks) {
            double af = asub[ks * 4 + lk][wv * 16 + lr];
            double bf[4];
            #pragma unroll
            for (int c = 0; c < 4; ++c) bf[c] = bsub[ks * 4 + lk][c * 16 + lr];
            #pragma unroll
            for (int c = 0; c < 4; ++c)
                acc[c] = __builtin_amdgcn_mfma_f64_16x16x4f64(af, bf[c], acc[c], 0, 0, 0);
        }
    }

    // neg_frc = deg_out[i] + deg_in[j] - 4 - 0.5*T   (placement via probed layout)
    #pragma unroll
    for (int g = 0; g < 4; ++g) {
        int i = i0 + wv * 16 + prow[g];
        double doi = dout[h * MBLK + i] - 4.0;
        #pragma unroll
        for (int c = 0; c < 4; ++c) {
            int j = j0 + c * 16 + pcol[g];
            neg[((size_t)h << 20) + ((size_t)i << 10) + j] =
                doi + din[h * MBLK + j] - 0.5 * acc[c][g];
        }
    }
}

// ---------------- exact k-th largest per row + mask write (fused) ----------------
__device__ inline u64 sortable64(double f) {
    u64 b = (u64)__double_as_longlong(f);
    return (b & 0x8000000000000000ull) ? ~b : (b | 0x8000000000000000ull);
}

__global__ __launch_bounds__(256) void topk_mask_kernel(const double* __restrict__ neg,
                                                        int* __restrict__ out) {
    int r = blockIdx.x;            // 8192 rows
    int tid = threadIdx.x;
    const double* row = neg + ((size_t)r << 10);
    u64 v0 = sortable64(row[tid]);
    u64 v1 = sortable64(row[tid + 256]);
    u64 v2 = sortable64(row[tid + 512]);
    u64 v3 = sortable64(row[tid + 768]);

    __shared__ int part[4];
    u64 lo = 0, hi = ~0ull;
    while (lo < hi) {
        u64 span = hi - lo;
        u64 mid = lo + (span >> 1) + (span & 1);   // upper mid
        int c = (int)(v0 >= mid) + (int)(v1 >= mid) + (int)(v2 >= mid) + (int)(v3 >= mid);
        #pragma unroll
        for (int off = 1; off < 64; off <<= 1) c += __shfl_xor(c, off);
        if ((tid & 63) == 0) part[tid >> 6] = c;
        __syncthreads();
        int total = part[0] + part[1] + part[2] + part[3];
        if (total >= KKEEP) lo = mid; else hi = mid - 1;
        __syncthreads();
    }

    int i = r & 1023;              // diagonal index within this head's MxM
    int* orow = out + ((size_t)r << 10);
    orow[tid]       = (v0 >= lo || tid == i)         ? 1 : 0;
    orow[tid + 256] = (v1 >= lo || (tid + 256) == i) ? 1 : 0;
    orow[tid + 512] = (v2 >= lo || (tid + 512) == i) ? 1 : 0;
    orow[tid + 768] = (v3 >= lo || (tid + 768) == i) ? 1 : 0;
}

extern "C" void kernel_launch(void* const* d_in, const int* in_sizes, int n_in,
                              void* d_out, int out_size, void* d_ws, size_t ws_size,
                              hipStream_t stream) {
    const float* q = (const float*)d_in[0];
    const float* k = (const float*)d_in[1];
    int* out = (int*)d_out;
    char* ws = (char*)d_ws;

    float*  qc   = (float*)ws;                            //  4 MB
    float*  kc   = (float*)(ws + (4ull << 20));           //  4 MB
    double* A    = (double*)(ws + (8ull << 20));          // 64 MB
    double* neg  = (double*)(ws + (72ull << 20));         // 64 MB
    double* dgo  = (double*)(ws + (136ull << 20));        // 64 KB
    double* dgi  = dgo + 8192;                            // 64 KB

    coarsen_kernel<<<8192, 256, 0, stream>>>(q, qc);
    coarsen_kernel<<<8192, 256, 0, stream>>>(k, kc);
    affinity_kernel<<<2048, 256, 0, stream>>>(qc, kc, A);
    degout_kernel<<<2048, 256, 0, stream>>>(A, dgo);
    degin_kernel<<<128, 256, 0, stream>>>(A, dgi);
    tri_kernel<<<dim3(16, 16, 8), 256, 0, stream>>>(A, dgo, dgi, neg);
    topk_mask_kernel<<<8192, 256, 0, stream>>>(neg, out);
}

// Round 9
// 710.945 us; speedup vs baseline: 1.0488x; 1.0488x over previous
//
#include <hip/hip_runtime.h>

typedef unsigned int u32;
typedef unsigned long long u64;
typedef double f64x4 __attribute__((ext_vector_type(4)));

#define NHEAD 8
#define NTOK 65536
#define DIM 128
#define MBLK 1024
#define KKEEP 52

// ---------------- coarsen: pick max-L2 token per 64-token block ----------------
__global__ __launch_bounds__(256) void coarsen_kernel(const float* __restrict__ x,
                                                      float* __restrict__ xc) {
    int b = blockIdx.x;              // 0..8191  (h * 1024 + mb)
    int h = b >> 10, mb = b & 1023;
    const float4* b4 = (const float4*)(x + ((size_t)h * NTOK + (size_t)mb * 64) * DIM);
    int tid = threadIdx.x;

    __shared__ double norms[64];
    __shared__ int best;

    #pragma unroll
    for (int u = 0; u < 8; ++u) {
        int f = tid + u * 256;               // f>>5 = token, f&31 = lane's f4 within token
        float4 v = b4[f];
        double s = (double)v.x * v.x + (double)v.y * v.y + (double)v.z * v.z + (double)v.w * v.w;
        #pragma unroll
        for (int off = 1; off < 32; off <<= 1) s += __shfl_xor(s, off);
        if ((tid & 31) == 0) norms[f >> 5] = s;
    }
    __syncthreads();

    if (tid < 64) {   // wave 0: argmax with first-index tie-break
        double v = norms[tid]; int idx = tid;
        #pragma unroll
        for (int off = 32; off; off >>= 1) {
            double ov = __shfl_down(v, off);
            int oi = __shfl_down(idx, off);
            if (ov > v || (ov == v && oi < idx)) { v = ov; idx = oi; }
        }
        if (tid == 0) best = idx;
    }
    __syncthreads();

    if (tid < 32) {
        float4* dst = (float4*)(xc + ((size_t)h * MBLK + mb) * DIM);
        dst[tid] = b4[best * 32 + tid];
    }
}

// ---------------- affinity: A[h] = relu(qc kc^T * scale), fp64 out ----------------
__global__ __launch_bounds__(256) void affinity_kernel(const float* __restrict__ qc,
                                                       const float* __restrict__ kc,
                                                       double* __restrict__ A) {
    __shared__ double qs[32][70];   // [d][i], padded
    __shared__ double ks[32][70];   // [d][j]
    int b = blockIdx.x;             // 8 * 16 * 16 = 2048
    int h = b >> 8, ti = (b >> 4) & 15, tj = b & 15;
    int i0 = ti * 64, j0 = tj * 64;
    int tid = threadIdx.x, tx = tid & 15, ty = tid >> 4;

    double acc[4][4] = {};
    const float4* qg = (const float4*)(qc + ((size_t)h * MBLK + i0) * DIM);
    const float4* kg = (const float4*)(kc + ((size_t)h * MBLK + j0) * DIM);

    for (int dk = 0; dk < 4; ++dk) {        // K=128 in chunks of 32
        __syncthreads();
        #pragma unroll
        for (int u = 0; u < 2; ++u) {
            int f = tid + u * 256;          // 0..511 ; row = f>>3, dp = f&7
            int row = f >> 3, dp = f & 7;
            float4 qv = qg[row * 32 + dk * 8 + dp];
            float4 kv = kg[row * 32 + dk * 8 + dp];
            int d0 = dp * 4;
            qs[d0 + 0][row] = qv.x; qs[d0 + 1][row] = qv.y;
            qs[d0 + 2][row] = qv.z; qs[d0 + 3][row] = qv.w;
            ks[d0 + 0][row] = kv.x; ks[d0 + 1][row] = kv.y;
            ks[d0 + 2][row] = kv.z; ks[d0 + 3][row] = kv.w;
        }
        __syncthreads();
        #pragma unroll
        for (int d = 0; d < 32; ++d) {
            double a[4], bb[4];
            *(double2*)&a[0]  = *(const double2*)&qs[d][ty * 2];
            *(double2*)&a[2]  = *(const double2*)&qs[d][32 + ty * 2];
            *(double2*)&bb[0] = *(const double2*)&ks[d][tx * 2];
            *(double2*)&bb[2] = *(const double2*)&ks[d][32 + tx * 2];
            #pragma unroll
            for (int r = 0; r < 4; ++r)
                #pragma unroll
                for (int c = 0; c < 4; ++c)
                    acc[r][c] += a[r] * bb[c];
        }
    }

    const double scale = 1.0 / sqrt(128.0);   // IEEE-exact, matches python
    #pragma unroll
    for (int r = 0; r < 4; ++r) {
        int i = i0 + (r >> 1) * 32 + ty * 2 + (r & 1);
        #pragma unroll
        for (int c = 0; c < 4; c += 2) {
            int j = j0 + (c >> 1) * 32 + tx * 2;
            double2 v;
            double v0 = acc[r][c]     * scale; if (v0 < 0.0) v0 = 0.0;
            double v1 = acc[r][c + 1] * scale; if (v1 < 0.0) v1 = 0.0;
            v.x = v0; v.y = v1;
            *(double2*)&A[((size_t)h << 20) + ((size_t)i << 10) + j] = v;
        }
    }
}

// ---------------- degrees ----------------
__global__ __launch_bounds__(256) void degout_kernel(const double* __restrict__ A,
                                                     double* __restrict__ dout) {
    int r = blockIdx.x * 4 + (threadIdx.x >> 6);   // 8192 rows, grid 2048
    int lane = threadIdx.x & 63;
    const double* row = A + ((size_t)r << 10);
    double s = 0.0;
    #pragma unroll
    for (int it = 0; it < 16; ++it) s += row[lane + it * 64];
    #pragma unroll
    for (int off = 1; off < 64; off <<= 1) s += __shfl_xor(s, off);
    if (lane == 0) dout[r] = s;
}

__global__ __launch_bounds__(256) void degin_kernel(const double* __restrict__ A,
                                                    double* __restrict__ din) {
    int b = blockIdx.x;           // 8 heads * 16 colgroups = 128
    int h = b >> 4, cg = b & 15;
    int tid = threadIdx.x;
    int col = cg * 64 + (tid & 63);
    int rc = tid >> 6;            // 0..3, each sums 256 rows
    const double* base = A + ((size_t)h << 20) + col;
    double s = 0.0;
    for (int i = rc * 256; i < rc * 256 + 256; ++i) s += base[(size_t)i << 10];
    __shared__ double part[4][64];
    part[rc][tid & 63] = s;
    __syncthreads();
    if (tid < 64) din[h * MBLK + cg * 64 + tid] = part[0][tid] + part[1][tid] + part[2][tid] + part[3][tid];
}

// ---------------- triangles + neg_frc via fp64 MFMA, 512-thread + register prefetch ----
// 128x128 tile, BK=32, 8 waves (wave = 16 rows x 128 cols, acc = 8 f64x4).
// Register prefetch: tile t+1's global loads are issued right after barrier-a and
// stay in flight under the ~4096-cycle MFMA block; ds_write happens after barrier-b.
// Same barrier count as the plain loop; +16 VGPR (still 2 blocks/CU, 16 waves).
// A frag: row=lane&15, k=lane>>4 ; B frag: col=lane&15, k=lane>>4.
// C/D layout measured at runtime via 4-MFMA probe (exact-integer D = i*16+j).
__global__ __launch_bounds__(512, 4) void tri_kernel(const double* __restrict__ A,
                                                     const double* __restrict__ dout,
                                                     const double* __restrict__ din,
                                                     double* __restrict__ neg) {
    __shared__ double asub[32][132];   // [k][i]
    __shared__ double bsub[32][132];   // [k][j]
    int h = blockIdx.z, ti = blockIdx.y, tj = blockIdx.x;
    int i0 = ti * 128, j0 = tj * 128;
    int tid = threadIdx.x;
    int wv = tid >> 6, lane = tid & 63;
    int lr = lane & 15, lk = lane >> 4;

    // ---- layout probe: D[i][j] = i*16 + j ----
    f64x4 probe = {0.0, 0.0, 0.0, 0.0};
    #pragma unroll
    for (int t = 0; t < 4; ++t) {
        double pa = (lr == 4 * t + lk) ? 1.0 : 0.0;        // A[i][k] = (i == 4t+k)
        double pb = (double)((4 * t + lk) * 16 + lr);      // B[k][j] = (4t+k)*16 + j
        probe = __builtin_amdgcn_mfma_f64_16x16x4f64(pa, pb, probe, 0, 0, 0);
    }
    int prow[4], pcol[4];
    #pragma unroll
    for (int g = 0; g < 4; ++g) {
        int v = (int)probe[g];
        prow[g] = v >> 4;
        pcol[g] = v & 15;
    }

    f64x4 acc[8];
    #pragma unroll
    for (int c = 0; c < 8; ++c) {
        f64x4 z = {0.0, 0.0, 0.0, 0.0};
        acc[c] = z;
    }

    const double* Ah = A + ((size_t)h << 20);

    // staging coords: u=0..3, f = tid + u*512 in [0,2048)
    //   A tile 128 rows x 16 double2 (k): arow = f>>4, akp = f&15
    //   B tile 32 k-rows x 64 double2 (j): bkr = f>>6, bc2 = f&63
    int arow[4], akp[4], bkr[4], bc2[4];
    #pragma unroll
    for (int u = 0; u < 4; ++u) {
        int f = tid + u * 512;
        arow[u] = f >> 4;  akp[u] = f & 15;
        bkr[u]  = f >> 6;  bc2[u] = f & 63;
    }

    double2 aR[4], bR[4];

    // prologue: load tile 0 into regs, write LDS
    #pragma unroll
    for (int u = 0; u < 4; ++u)
        aR[u] = *(const double2*)&Ah[((size_t)(i0 + arow[u]) << 10) + akp[u] * 2];
    #pragma unroll
    for (int u = 0; u < 4; ++u)
        bR[u] = *(const double2*)&Ah[((size_t)bkr[u] << 10) + j0 + bc2[u] * 2];
    #pragma unroll
    for (int u = 0; u < 4; ++u) {
        asub[akp[u] * 2][arow[u]] = aR[u].x;
        asub[akp[u] * 2 + 1][arow[u]] = aR[u].y;
        *(double2*)&bsub[bkr[u]][bc2[u] * 2] = bR[u];
    }

    for (int kt = 0; kt < 1024; kt += 32) {
        __syncthreads();                          // barrier-a: LDS tile kt visible
        bool more = (kt + 32) < 1024;
        if (more) {                               // issue t+1 loads; in flight under MFMA
            int ktn = kt + 32;
            #pragma unroll
            for (int u = 0; u < 4; ++u)
                aR[u] = *(const double2*)&Ah[((size_t)(i0 + arow[u]) << 10) + ktn + akp[u] * 2];
            #pragma unroll
            for (int u = 0; u < 4; ++u)
                bR[u] = *(const double2*)&Ah[((size_t)(ktn + bkr[u]) << 10) + j0 + bc2[u] * 2];
        }
        #pragma unroll
        for (int ks = 0; ks < 8; ++ks) {
            double af = asub[ks * 4 + lk][wv * 16 + lr];
            double bf[8];
            #pragma unroll
            for (int c = 0; c < 8; ++c) bf[c] = bsub[ks * 4 + lk][c * 16 + lr];
            #pragma unroll
            for (int c = 0; c < 8; ++c)
                acc[c] = __builtin_amdgcn_mfma_f64_16x16x4f64(af, bf[c], acc[c], 0, 0, 0);
        }
        __syncthreads();                          // barrier-b: all reads of LDS done
        if (more) {                               // overwrite LDS with tile t+1
            #pragma unroll
            for (int u = 0; u < 4; ++u) {
                asub[akp[u] * 2][arow[u]] = aR[u].x;
                asub[akp[u] * 2 + 1][arow[u]] = aR[u].y;
                *(double2*)&bsub[bkr[u]][bc2[u] * 2] = bR[u];
            }
        }
    }

    // neg_frc = deg_out[i] + deg_in[j] - 4 - 0.5*T   (placement via probed layout)
    #pragma unroll
    for (int g = 0; g < 4; ++g) {
        int i = i0 + wv * 16 + prow[g];
        double doi = dout[h * MBLK + i] - 4.0;
        #pragma unroll
        for (int c = 0; c < 8; ++c) {
            int j = j0 + c * 16 + pcol[g];
            neg[((size_t)h << 20) + ((size_t)i << 10) + j] =
                doi + din[h * MBLK + j] - 0.5 * acc[c][g];
        }
    }
}

// ---------------- exact k-th largest per row + mask write (fused) ----------------
__device__ inline u64 sortable64(double f) {
    u64 b = (u64)__double_as_longlong(f);
    return (b & 0x8000000000000000ull) ? ~b : (b | 0x8000000000000000ull);
}

__global__ __launch_bounds__(256) void topk_mask_kernel(const double* __restrict__ neg,
                                                        int* __restrict__ out) {
    int r = blockIdx.x;            // 8192 rows
    int tid = threadIdx.x;
    const double* row = neg + ((size_t)r << 10);
    u64 v0 = sortable64(row[tid]);
    u64 v1 = sortable64(row[tid + 256]);
    u64 v2 = sortable64(row[tid + 512]);
    u64 v3 = sortable64(row[tid + 768]);

    __shared__ int part[4];
    u64 lo = 0, hi = ~0ull;
    while (lo < hi) {
        u64 span = hi - lo;
        u64 mid = lo + (span >> 1) + (span & 1);   // upper mid
        int c = (int)(v0 >= mid) + (int)(v1 >= mid) + (int)(v2 >= mid) + (int)(v3 >= mid);
        #pragma unroll
        for (int off = 1; off < 64; off <<= 1) c += __shfl_xor(c, off);
        if ((tid & 63) == 0) part[tid >> 6] = c;
        __syncthreads();
        int total = part[0] + part[1] + part[2] + part[3];
        if (total >= KKEEP) lo = mid; else hi = mid - 1;
        __syncthreads();
    }

    int i = r & 1023;              // diagonal index within this head's MxM
    int* orow = out + ((size_t)r << 10);
    orow[tid]       = (v0 >= lo || tid == i)         ? 1 : 0;
    orow[tid + 256] = (v1 >= lo || (tid + 256) == i) ? 1 : 0;
    orow[tid + 512] = (v2 >= lo || (tid + 512) == i) ? 1 : 0;
    orow[tid + 768] = (v3 >= lo || (tid + 768) == i) ? 1 : 0;
}

extern "C" void kernel_launch(void* const* d_in, const int* in_sizes, int n_in,
                              void* d_out, int out_size, void* d_ws, size_t ws_size,
                              hipStream_t stream) {
    const float* q = (const float*)d_in[0];
    const float* k = (const float*)d_in[1];
    int* out = (int*)d_out;
    char* ws = (char*)d_ws;

    float*  qc   = (float*)ws;                            //  4 MB
    float*  kc   = (float*)(ws + (4ull << 20));           //  4 MB
    double* A    = (double*)(ws + (8ull << 20));          // 64 MB
    double* neg  = (double*)(ws + (72ull << 20));         // 64 MB
    double* dgo  = (double*)(ws + (136ull << 20));        // 64 KB
    double* dgi  = dgo + 8192;                            // 64 KB

    coarsen_kernel<<<8192, 256, 0, stream>>>(q, qc);
    coarsen_kernel<<<8192, 256, 0, stream>>>(k, kc);
    affinity_kernel<<<2048, 256, 0, stream>>>(qc, kc, A);
    degout_kernel<<<2048, 256, 0, stream>>>(A, dgo);
    degin_kernel<<<128, 256, 0, stream>>>(A, dgi);
    tri_kernel<<<dim3(8, 8, 8), 512, 0, stream>>>(A, dgo, dgi, neg);
    topk_mask_kernel<<<8192, 256, 0, stream>>>(neg, out);
}

// Round 11
// 569.733 us; speedup vs baseline: 1.3087x; 1.2479x over previous
//
#include <hip/hip_runtime.h>

typedef unsigned int u32;
typedef unsigned long long u64;
typedef double f64x4 __attribute__((ext_vector_type(4)));

#define NHEAD 8
#define NTOK 65536
#define DIM 128
#define MBLK 1024
#define KKEEP 52

// ---------------- coarsen: pick max-L2 token per 64-token block ----------------
__global__ __launch_bounds__(256) void coarsen_kernel(const float* __restrict__ x,
                                                      float* __restrict__ xc) {
    int b = blockIdx.x;              // 0..8191  (h * 1024 + mb)
    int h = b >> 10, mb = b & 1023;
    const float4* b4 = (const float4*)(x + ((size_t)h * NTOK + (size_t)mb * 64) * DIM);
    int tid = threadIdx.x;

    __shared__ double norms[64];
    __shared__ int best;

    #pragma unroll
    for (int u = 0; u < 8; ++u) {
        int f = tid + u * 256;               // f>>5 = token, f&31 = lane's f4 within token
        float4 v = b4[f];
        double s = (double)v.x * v.x + (double)v.y * v.y + (double)v.z * v.z + (double)v.w * v.w;
        #pragma unroll
        for (int off = 1; off < 32; off <<= 1) s += __shfl_xor(s, off);
        if ((tid & 31) == 0) norms[f >> 5] = s;
    }
    __syncthreads();

    if (tid < 64) {   // wave 0: argmax with first-index tie-break
        double v = norms[tid]; int idx = tid;
        #pragma unroll
        for (int off = 32; off; off >>= 1) {
            double ov = __shfl_down(v, off);
            int oi = __shfl_down(idx, off);
            if (ov > v || (ov == v && oi < idx)) { v = ov; idx = oi; }
        }
        if (tid == 0) best = idx;
    }
    __syncthreads();

    if (tid < 32) {
        float4* dst = (float4*)(xc + ((size_t)h * MBLK + mb) * DIM);
        dst[tid] = b4[best * 32 + tid];
    }
}

// ------- affinity: A[h] = relu(qc kc^T * scale), fp64 out + per-tile degree partials ----
// Each (h,ti,tj) 64x64 tile also writes its 64 row-sums to pout[h][ti][tj][64] and
// 64 col-sums to pin[h][tj][ti][64]; deg_reduce sums the 16 tiles in FIXED order
// (deterministic; removes the degout/degin full re-reads of A).
__global__ __launch_bounds__(256) void affinity_kernel(const float* __restrict__ qc,
                                                       const float* __restrict__ kc,
                                                       double* __restrict__ A,
                                                       double* __restrict__ pout,
                                                       double* __restrict__ pin) {
    __shared__ double qs[32][70];   // [d][i], padded
    __shared__ double ks[32][70];   // [d][j]
    __shared__ double cred[4][64];  // per-wave col partials
    int b = blockIdx.x;             // 8 * 16 * 16 = 2048
    int h = b >> 8, ti = (b >> 4) & 15, tj = b & 15;
    int i0 = ti * 64, j0 = tj * 64;
    int tid = threadIdx.x, tx = tid & 15, ty = tid >> 4;

    double acc[4][4] = {};
    const float4* qg = (const float4*)(qc + ((size_t)h * MBLK + i0) * DIM);
    const float4* kg = (const float4*)(kc + ((size_t)h * MBLK + j0) * DIM);

    for (int dk = 0; dk < 4; ++dk) {        // K=128 in chunks of 32
        __syncthreads();
        #pragma unroll
        for (int u = 0; u < 2; ++u) {
            int f = tid + u * 256;          // 0..511 ; row = f>>3, dp = f&7
            int row = f >> 3, dp = f & 7;
            float4 qv = qg[row * 32 + dk * 8 + dp];
            float4 kv = kg[row * 32 + dk * 8 + dp];
            int d0 = dp * 4;
            qs[d0 + 0][row] = qv.x; qs[d0 + 1][row] = qv.y;
            qs[d0 + 2][row] = qv.z; qs[d0 + 3][row] = qv.w;
            ks[d0 + 0][row] = kv.x; ks[d0 + 1][row] = kv.y;
            ks[d0 + 2][row] = kv.z; ks[d0 + 3][row] = kv.w;
        }
        __syncthreads();
        #pragma unroll
        for (int d = 0; d < 32; ++d) {
            double a[4], bb[4];
            *(double2*)&a[0]  = *(const double2*)&qs[d][ty * 2];
            *(double2*)&a[2]  = *(const double2*)&qs[d][32 + ty * 2];
            *(double2*)&bb[0] = *(const double2*)&ks[d][tx * 2];
            *(double2*)&bb[2] = *(const double2*)&ks[d][32 + tx * 2];
            #pragma unroll
            for (int r = 0; r < 4; ++r)
                #pragma unroll
                for (int c = 0; c < 4; ++c)
                    acc[r][c] += a[r] * bb[c];
        }
    }

    const double scale = 1.0 / sqrt(128.0);   // IEEE-exact, matches python
    double rl[4][4];
    #pragma unroll
    for (int r = 0; r < 4; ++r)
        #pragma unroll
        for (int c = 0; c < 4; ++c) {
            double v = acc[r][c] * scale;
            rl[r][c] = (v < 0.0) ? 0.0 : v;
        }

    #pragma unroll
    for (int r = 0; r < 4; ++r) {
        int i = i0 + (r >> 1) * 32 + ty * 2 + (r & 1);
        #pragma unroll
        for (int c = 0; c < 4; c += 2) {
            int j = j0 + (c >> 1) * 32 + tx * 2;
            double2 v; v.x = rl[r][c]; v.y = rl[r][c + 1];
            *(double2*)&A[((size_t)h << 20) + ((size_t)i << 10) + j] = v;
        }
    }

    // ---- row partials: reduce over tx (lane bits 0-3) ----
    int hidx = h * 16;
    #pragma unroll
    for (int r = 0; r < 4; ++r) {
        double rp = rl[r][0] + rl[r][1] + rl[r][2] + rl[r][3];
        #pragma unroll
        for (int off = 1; off < 16; off <<= 1) rp += __shfl_xor(rp, off);
        if (tx == 0)
            pout[(((size_t)(hidx + ti) * 16 + tj) << 6) + (r >> 1) * 32 + ty * 2 + (r & 1)] = rp;
    }

    // ---- col partials: reduce over ty (lane bits 4-5 within wave, then LDS over waves) ----
    int wv = tid >> 6, lane = tid & 63;
    #pragma unroll
    for (int c = 0; c < 4; ++c) {
        double cp = rl[0][c] + rl[1][c] + rl[2][c] + rl[3][c];
        cp += __shfl_xor(cp, 16);
        cp += __shfl_xor(cp, 32);
        if (lane < 16) cred[wv][(c >> 1) * 32 + lane * 2 + (c & 1)] = cp;
    }
    __syncthreads();
    if (tid < 64)
        pin[(((size_t)(hidx + tj) * 16 + ti) << 6) + tid] =
            cred[0][tid] + cred[1][tid] + cred[2][tid] + cred[3][tid];
}

// ---------------- degree reduce: fixed-order 16-term sums (deterministic) ----------------
__global__ __launch_bounds__(256) void deg_reduce_kernel(const double* __restrict__ pout,
                                                         const double* __restrict__ pin,
                                                         double* __restrict__ dgo,
                                                         double* __restrict__ dgi) {
    int t = blockIdx.x * 256 + threadIdx.x;   // 0..16383
    const double* src = (t < 8192) ? pout : pin;
    double* dst = (t < 8192) ? dgo : dgi;
    int r = t & 8191;
    int hi = r >> 6, rr = r & 63;
    double s = 0.0;
    #pragma unroll
    for (int tj = 0; tj < 16; ++tj) s += src[(((size_t)hi * 16 + tj) << 6) + rr];
    dst[r] = s;
}

// ---------------- triangles + neg_frc via fp64 MFMA (R7 structure, conflict-fixed) -------
// 128x128 tile, BK=32, 512 threads, acc = 8 f64x4 (64 AGPR) -> 4 waves/SIMD (reg-capped).
// asub padded 131 (odd): transposed ds_write bank-stride 12 mod 32 -> 2-way (free),
// was 16 mod 32 -> 8-way (15% of CU time in R7). bsub stays 132 (16B-aligned b128).
// A frag: row=lane&15, k=lane>>4 ; B frag: col=lane&15, k=lane>>4.
// C/D layout measured at runtime via 4-MFMA probe (exact-integer D = i*16+j).
__global__ __launch_bounds__(512, 4) void tri_kernel(const double* __restrict__ A,
                                                     const double* __restrict__ dout,
                                                     const double* __restrict__ din,
                                                     double* __restrict__ neg) {
    __shared__ double asub[32][131];   // [k][i]  (odd pad: conflict-free transposed writes)
    __shared__ double bsub[32][132];   // [k][j]
    int h = blockIdx.z, ti = blockIdx.y, tj = blockIdx.x;
    int i0 = ti * 128, j0 = tj * 128;
    int tid = threadIdx.x;
    int wv = tid >> 6, lane = tid & 63;
    int lr = lane & 15, lk = lane >> 4;

    // ---- layout probe: D[i][j] = i*16 + j ----
    f64x4 probe = {0.0, 0.0, 0.0, 0.0};
    #pragma unroll
    for (int t = 0; t < 4; ++t) {
        double pa = (lr == 4 * t + lk) ? 1.0 : 0.0;        // A[i][k] = (i == 4t+k)
        double pb = (double)((4 * t + lk) * 16 + lr);      // B[k][j] = (4t+k)*16 + j
        probe = __builtin_amdgcn_mfma_f64_16x16x4f64(pa, pb, probe, 0, 0, 0);
    }
    int prow[4], pcol[4];
    #pragma unroll
    for (int g = 0; g < 4; ++g) {
        int v = (int)probe[g];
        prow[g] = v >> 4;
        pcol[g] = v & 15;
    }

    f64x4 acc[8];
    #pragma unroll
    for (int c = 0; c < 8; ++c) {
        f64x4 z = {0.0, 0.0, 0.0, 0.0};
        acc[c] = z;
    }

    const double* Ah = A + ((size_t)h << 20);

    // staging coords: u=0..3, f = tid + u*512 in [0,2048)
    //   A tile 128 rows x 16 double2 (k): arow = f>>4, akp = f&15
    //   B tile 32 k-rows x 64 double2 (j): bkr = f>>6, bc2 = f&63
    int arow[4], akp[4], bkr[4], bc2[4];
    #pragma unroll
    for (int u = 0; u < 4; ++u) {
        int f = tid + u * 512;
        arow[u] = f >> 4;  akp[u] = f & 15;
        bkr[u]  = f >> 6;  bc2[u] = f & 63;
    }

    for (int kt = 0; kt < 1024; kt += 32) {
        __syncthreads();
        #pragma unroll
        for (int u = 0; u < 4; ++u) {          // A tile 128x32 (transposed store)
            double2 v = *(const double2*)&Ah[((size_t)(i0 + arow[u]) << 10) + kt + akp[u] * 2];
            asub[akp[u] * 2][arow[u]] = v.x;
            asub[akp[u] * 2 + 1][arow[u]] = v.y;
        }
        #pragma unroll
        for (int u = 0; u < 4; ++u) {          // B tile 32x128 (direct)
            double2 v = *(const double2*)&Ah[((size_t)(kt + bkr[u]) << 10) + j0 + bc2[u] * 2];
            *(double2*)&bsub[bkr[u]][bc2[u] * 2] = v;
        }
        __syncthreads();
        #pragma unroll
        for (int ks = 0; ks < 8; ++ks) {
            double af = asub[ks * 4 + lk][wv * 16 + lr];
            double bf[8];
            #pragma unroll
            for (int c = 0; c < 8; ++c) bf[c] = bsub[ks * 4 + lk][c * 16 + lr];
            #pragma unroll
            for (int c = 0; c < 8; ++c)
                acc[c] = __builtin_amdgcn_mfma_f64_16x16x4f64(af, bf[c], acc[c], 0, 0, 0);
        }
    }

    // neg_frc = deg_out[i] + deg_in[j] - 4 - 0.5*T   (placement via probed layout)
    #pragma unroll
    for (int g = 0; g < 4; ++g) {
        int i = i0 + wv * 16 + prow[g];
        double doi = dout[h * MBLK + i] - 4.0;
        #pragma unroll
        for (int c = 0; c < 8; ++c) {
            int j = j0 + c * 16 + pcol[g];
            neg[((size_t)h << 20) + ((size_t)i << 10) + j] =
                doi + din[h * MBLK + j] - 0.5 * acc[c][g];
        }
    }
}

// ---------------- exact k-th largest + mask, single wave per row (no barriers) ----------
__device__ inline u64 sortable64(double f) {
    u64 b = (u64)__double_as_longlong(f);
    return (b & 0x8000000000000000ull) ? ~b : (b | 0x8000000000000000ull);
}

__global__ __launch_bounds__(64) void topk_mask_kernel(const double* __restrict__ neg,
                                                       int* __restrict__ out) {
    int r = blockIdx.x;            // 8192 rows
    int l = threadIdx.x;           // 64 lanes
    const double* row = neg + ((size_t)r << 10);
    u64 v[16];
    #pragma unroll
    for (int m = 0; m < 16; ++m) v[m] = sortable64(row[l + m * 64]);

    u64 lo = 0, hi = ~0ull;
    while (lo < hi) {
        u64 span = hi - lo;
        u64 mid = lo + (span >> 1) + (span & 1);   // upper mid
        int c = 0;
        #pragma unroll
        for (int m = 0; m < 16; ++m) c += (int)(v[m] >= mid);
        #pragma unroll
        for (int off = 1; off < 64; off <<= 1) c += __shfl_xor(c, off);
        if (c >= KKEEP) lo = mid; else hi = mid - 1;   // uniform across lanes
    }

    int i = r & 1023;              // diagonal index within this head's MxM
    int* orow = out + ((size_t)r << 10);
    #pragma unroll
    for (int m = 0; m < 16; ++m)
        orow[l + m * 64] = (v[m] >= lo || (l + m * 64) == i) ? 1 : 0;
}

extern "C" void kernel_launch(void* const* d_in, const int* in_sizes, int n_in,
                              void* d_out, int out_size, void* d_ws, size_t ws_size,
                              hipStream_t stream) {
    const float* q = (const float*)d_in[0];
    const float* k = (const float*)d_in[1];
    int* out = (int*)d_out;
    char* ws = (char*)d_ws;

    float*  qc   = (float*)ws;                            //  4 MB
    float*  kc   = (float*)(ws + (4ull << 20));           //  4 MB
    double* A    = (double*)(ws + (8ull << 20));          // 64 MB
    double* neg  = (double*)(ws + (72ull << 20));         // 64 MB
    double* dgo  = (double*)(ws + (136ull << 20));        // 64 KB
    double* dgi  = dgo + 8192;                            // 64 KB
    double* pout = dgi + 8192;                            //  1 MB (8*16*16*64 doubles)
    double* pin  = pout + 131072;                         //  1 MB

    coarsen_kernel<<<8192, 256, 0, stream>>>(q, qc);
    coarsen_kernel<<<8192, 256, 0, stream>>>(k, kc);
    affinity_kernel<<<2048, 256, 0, stream>>>(qc, kc, A, pout, pin);
    deg_reduce_kernel<<<64, 256, 0, stream>>>(pout, pin, dgo, dgi);
    tri_kernel<<<dim3(8, 8, 8), 512, 0, stream>>>(A, dgo, dgi, neg);
    topk_mask_kernel<<<8192, 64, 0, stream>>>(neg, out);
}

// Round 12
// 517.546 us; speedup vs baseline: 1.4407x; 1.1008x over previous
//
#include <hip/hip_runtime.h>

typedef unsigned int u32;
typedef unsigned long long u64;
typedef double f64x4 __attribute__((ext_vector_type(4)));

#define NHEAD 8
#define NTOK 65536
#define DIM 128
#define MBLK 1024
#define KKEEP 52

// ---------------- coarsen: pick max-L2 token per 64-token block (q and k fused) --------
__global__ __launch_bounds__(256) void coarsen_kernel(const float* __restrict__ q,
                                                      const float* __restrict__ k,
                                                      float* __restrict__ qc,
                                                      float* __restrict__ kc) {
    int bb = blockIdx.x;             // 0..16383 ; first half q, second half k
    const float* x = (bb < 8192) ? q : k;
    float* xc = (bb < 8192) ? qc : kc;
    int b = bb & 8191;
    int h = b >> 10, mb = b & 1023;
    const float4* b4 = (const float4*)(x + ((size_t)h * NTOK + (size_t)mb * 64) * DIM);
    int tid = threadIdx.x;

    __shared__ double norms[64];
    __shared__ int best;

    #pragma unroll
    for (int u = 0; u < 8; ++u) {
        int f = tid + u * 256;               // f>>5 = token, f&31 = lane's f4 within token
        float4 v = b4[f];
        double s = (double)v.x * v.x + (double)v.y * v.y + (double)v.z * v.z + (double)v.w * v.w;
        #pragma unroll
        for (int off = 1; off < 32; off <<= 1) s += __shfl_xor(s, off);
        if ((tid & 31) == 0) norms[f >> 5] = s;
    }
    __syncthreads();

    if (tid < 64) {   // wave 0: argmax with first-index tie-break
        double v = norms[tid]; int idx = tid;
        #pragma unroll
        for (int off = 32; off; off >>= 1) {
            double ov = __shfl_down(v, off);
            int oi = __shfl_down(idx, off);
            if (ov > v || (ov == v && oi < idx)) { v = ov; idx = oi; }
        }
        if (tid == 0) best = idx;
    }
    __syncthreads();

    if (tid < 32) {
        float4* dst = (float4*)(xc + ((size_t)h * MBLK + mb) * DIM);
        dst[tid] = b4[best * 32 + tid];
    }
}

// ------- affinity: A[h] = relu(qc kc^T * scale), fp64 out + per-tile degree partials ----
__global__ __launch_bounds__(256) void affinity_kernel(const float* __restrict__ qc,
                                                       const float* __restrict__ kc,
                                                       double* __restrict__ A,
                                                       double* __restrict__ pout,
                                                       double* __restrict__ pin) {
    __shared__ double qs[32][70];   // [d][i], padded
    __shared__ double ks[32][70];   // [d][j]
    __shared__ double cred[4][64];  // per-wave col partials
    int b = blockIdx.x;             // 8 * 16 * 16 = 2048
    int h = b >> 8, ti = (b >> 4) & 15, tj = b & 15;
    int i0 = ti * 64, j0 = tj * 64;
    int tid = threadIdx.x, tx = tid & 15, ty = tid >> 4;

    double acc[4][4] = {};
    const float4* qg = (const float4*)(qc + ((size_t)h * MBLK + i0) * DIM);
    const float4* kg = (const float4*)(kc + ((size_t)h * MBLK + j0) * DIM);

    for (int dk = 0; dk < 4; ++dk) {        // K=128 in chunks of 32
        __syncthreads();
        #pragma unroll
        for (int u = 0; u < 2; ++u) {
            int f = tid + u * 256;          // 0..511 ; row = f>>3, dp = f&7
            int row = f >> 3, dp = f & 7;
            float4 qv = qg[row * 32 + dk * 8 + dp];
            float4 kv = kg[row * 32 + dk * 8 + dp];
            int d0 = dp * 4;
            qs[d0 + 0][row] = qv.x; qs[d0 + 1][row] = qv.y;
            qs[d0 + 2][row] = qv.z; qs[d0 + 3][row] = qv.w;
            ks[d0 + 0][row] = kv.x; ks[d0 + 1][row] = kv.y;
            ks[d0 + 2][row] = kv.z; ks[d0 + 3][row] = kv.w;
        }
        __syncthreads();
        #pragma unroll
        for (int d = 0; d < 32; ++d) {
            double a[4], bb[4];
            *(double2*)&a[0]  = *(const double2*)&qs[d][ty * 2];
            *(double2*)&a[2]  = *(const double2*)&qs[d][32 + ty * 2];
            *(double2*)&bb[0] = *(const double2*)&ks[d][tx * 2];
            *(double2*)&bb[2] = *(const double2*)&ks[d][32 + tx * 2];
            #pragma unroll
            for (int r = 0; r < 4; ++r)
                #pragma unroll
                for (int c = 0; c < 4; ++c)
                    acc[r][c] += a[r] * bb[c];
        }
    }

    const double scale = 1.0 / sqrt(128.0);   // IEEE-exact, matches python
    double rl[4][4];
    #pragma unroll
    for (int r = 0; r < 4; ++r)
        #pragma unroll
        for (int c = 0; c < 4; ++c) {
            double v = acc[r][c] * scale;
            rl[r][c] = (v < 0.0) ? 0.0 : v;
        }

    #pragma unroll
    for (int r = 0; r < 4; ++r) {
        int i = i0 + (r >> 1) * 32 + ty * 2 + (r & 1);
        #pragma unroll
        for (int c = 0; c < 4; c += 2) {
            int j = j0 + (c >> 1) * 32 + tx * 2;
            double2 v; v.x = rl[r][c]; v.y = rl[r][c + 1];
            *(double2*)&A[((size_t)h << 20) + ((size_t)i << 10) + j] = v;
        }
    }

    // ---- row partials: reduce over tx (lane bits 0-3) ----
    int hidx = h * 16;
    #pragma unroll
    for (int r = 0; r < 4; ++r) {
        double rp = rl[r][0] + rl[r][1] + rl[r][2] + rl[r][3];
        #pragma unroll
        for (int off = 1; off < 16; off <<= 1) rp += __shfl_xor(rp, off);
        if (tx == 0)
            pout[(((size_t)(hidx + ti) * 16 + tj) << 6) + (r >> 1) * 32 + ty * 2 + (r & 1)] = rp;
    }

    // ---- col partials ----
    int wv = tid >> 6, lane = tid & 63;
    #pragma unroll
    for (int c = 0; c < 4; ++c) {
        double cp = rl[0][c] + rl[1][c] + rl[2][c] + rl[3][c];
        cp += __shfl_xor(cp, 16);
        cp += __shfl_xor(cp, 32);
        if (lane < 16) cred[wv][(c >> 1) * 32 + lane * 2 + (c & 1)] = cp;
    }
    __syncthreads();
    if (tid < 64)
        pin[(((size_t)(hidx + tj) * 16 + ti) << 6) + tid] =
            cred[0][tid] + cred[1][tid] + cred[2][tid] + cred[3][tid];
}

// ---------------- degree reduce: fixed-order 16-term sums (deterministic) ----------------
__global__ __launch_bounds__(256) void deg_reduce_kernel(const double* __restrict__ pout,
                                                         const double* __restrict__ pin,
                                                         double* __restrict__ dgo,
                                                         double* __restrict__ dgi) {
    int t = blockIdx.x * 256 + threadIdx.x;   // 0..16383
    const double* src = (t < 8192) ? pout : pin;
    double* dst = (t < 8192) ? dgo : dgi;
    int r = t & 8191;
    int hi = r >> 6, rr = r & 63;
    double s = 0.0;
    #pragma unroll
    for (int tj = 0; tj < 16; ++tj) s += src[(((size_t)hi * 16 + tj) << 6) + rr];
    dst[r] = s;
}

// ---- async global->LDS helper (16B per lane; LDS dest = wave-uniform base + lane*16) ----
__device__ inline void gll16(const double* g, double* lds_base) {
    __builtin_amdgcn_global_load_lds((const __attribute__((address_space(1))) void*)g,
                                     (__attribute__((address_space(3))) void*)lds_base,
                                     16, 0, 0);
}

// ---------------- triangles + neg_frc: fp64 MFMA, dbuf via global_load_lds ----------------
// 128x128 tile, BK=16, 512 threads, acc = 8 f64x4 (64 AGPR) -> 4 waves/SIMD.
// Double buffer: tile t+1's loads issued direct-to-LDS right after the barrier, fly
// under the 2048-cyc MFMA phase; ONE __syncthreads per tile (implicit vmcnt(0) drain
// is cheap). Zero ds_writes, zero staging VGPRs (R9's spill trap avoided).
// asub row-major [128][16] with pre-swizzled global source: LDS row i, chunk-pos p
// holds A[i0+i][kt + 2*(p ^ (i&7))]; read applies the same XOR -> 2-way/free.
// bsub linear [16][128] (b64 reads at the structural floor).
// A frag: row=lane&15, k=lane>>4 ; B frag: col=lane&15, k=lane>>4.
// C/D layout measured at runtime via 4-MFMA probe (exact-integer D = i*16+j).
__global__ __launch_bounds__(512, 4) void tri_kernel(const double* __restrict__ A,
                                                     const double* __restrict__ dout,
                                                     const double* __restrict__ din,
                                                     double* __restrict__ neg) {
    __shared__ double lds[2][2][2048];   // [buf][0=A,1=B][2048 doubles] = 64 KB
    int h = blockIdx.z, ti = blockIdx.y, tj = blockIdx.x;
    int i0 = ti * 128, j0 = tj * 128;
    int tid = threadIdx.x;
    int wv = tid >> 6, lane = tid & 63;
    int lr = lane & 15, lk = lane >> 4;

    // ---- layout probe: D[i][j] = i*16 + j ----
    f64x4 probe = {0.0, 0.0, 0.0, 0.0};
    #pragma unroll
    for (int t = 0; t < 4; ++t) {
        double pa = (lr == 4 * t + lk) ? 1.0 : 0.0;        // A[i][k] = (i == 4t+k)
        double pb = (double)((4 * t + lk) * 16 + lr);      // B[k][j] = (4t+k)*16 + j
        probe = __builtin_amdgcn_mfma_f64_16x16x4f64(pa, pb, probe, 0, 0, 0);
    }
    int prow[4], pcol[4];
    #pragma unroll
    for (int g = 0; g < 4; ++g) {
        int v = (int)probe[g];
        prow[g] = v >> 4;
        pcol[g] = v & 15;
    }

    f64x4 acc[8];
    #pragma unroll
    for (int c = 0; c < 8; ++c) {
        f64x4 z = {0.0, 0.0, 0.0, 0.0};
        acc[c] = z;
    }

    const double* Ah = A + ((size_t)h << 20);

    // per-thread chunk coords (chunk = 16B = double2), f = tid + u*512 in [0,1024)
    int aRow[2], aPos[2], bRow[2], bPos[2];
    #pragma unroll
    for (int u = 0; u < 2; ++u) {
        int f = tid + u * 512;
        aRow[u] = f >> 3;  aPos[u] = f & 7;    // A tile: 128 rows x 8 chunks
        bRow[u] = f >> 6;  bPos[u] = f & 63;   // B tile: 16 rows x 64 chunks
    }

    // issue tile loads into buf: A chunk-pos p holds global chunk p ^ (row&7)
    #define ISSUE_TILE(BUF, KT)                                                        \
    {                                                                                  \
        int kt_ = (KT);                                                                \
        _Pragma("unroll")                                                              \
        for (int u = 0; u < 2; ++u) {                                                  \
            const double* gA = Ah + (size_t)(i0 + aRow[u]) * 1024 + kt_                \
                               + 2 * (aPos[u] ^ (aRow[u] & 7));                        \
            gll16(gA, &lds[BUF][0][(size_t)(wv * 64 + u * 512) * 2]);                  \
            const double* gB = Ah + (size_t)(kt_ + bRow[u]) * 1024 + j0 + 2 * bPos[u]; \
            gll16(gB, &lds[BUF][1][(size_t)(wv * 64 + u * 512) * 2]);                  \
        }                                                                              \
    }

    ISSUE_TILE(0, 0);
    __syncthreads();                       // implicit vmcnt(0): tile 0 ready

    int cur = 0;
    for (int kt = 0; kt < 1024; kt += 16) {
        if (kt + 16 < 1024) ISSUE_TILE(cur ^ 1, kt + 16);   // fly under MFMA phase

        const double* asub_d = &lds[cur][0][0];
        const double* bsub_d = &lds[cur][1][0];
        __builtin_amdgcn_s_setprio(1);
        #pragma unroll
        for (int ks = 0; ks < 4; ++ks) {
            int k = ks * 4 + lk;
            int i = wv * 16 + lr;
            double af = asub_d[i * 16 + ((k >> 1) ^ (i & 7)) * 2 + (k & 1)];
            double bf[8];
            #pragma unroll
            for (int c = 0; c < 8; ++c) bf[c] = bsub_d[k * 128 + c * 16 + lr];
            #pragma unroll
            for (int c = 0; c < 8; ++c)
                acc[c] = __builtin_amdgcn_mfma_f64_16x16x4f64(af, bf[c], acc[c], 0, 0, 0);
        }
        __builtin_amdgcn_s_setprio(0);

        __syncthreads();                   // drains t+1 loads; frees buf[cur] for overwrite
        cur ^= 1;
    }
    #undef ISSUE_TILE

    // neg_frc = deg_out[i] + deg_in[j] - 4 - 0.5*T   (placement via probed layout)
    #pragma unroll
    for (int g = 0; g < 4; ++g) {
        int i = i0 + wv * 16 + prow[g];
        double doi = dout[h * MBLK + i] - 4.0;
        #pragma unroll
        for (int c = 0; c < 8; ++c) {
            int j = j0 + c * 16 + pcol[g];
            neg[((size_t)h << 20) + ((size_t)i << 10) + j] =
                doi + din[h * MBLK + j] - 0.5 * acc[c][g];
        }
    }
}

// ---------------- exact k-th largest + mask, single wave per row (no barriers) ----------
__device__ inline u64 sortable64(double f) {
    u64 b = (u64)__double_as_longlong(f);
    return (b & 0x8000000000000000ull) ? ~b : (b | 0x8000000000000000ull);
}

__global__ __launch_bounds__(64) void topk_mask_kernel(const double* __restrict__ neg,
                                                       int* __restrict__ out) {
    int r = blockIdx.x;            // 8192 rows
    int l = threadIdx.x;           // 64 lanes
    const double* row = neg + ((size_t)r << 10);
    u64 v[16];
    #pragma unroll
    for (int m = 0; m < 16; ++m) v[m] = sortable64(row[l + m * 64]);

    u64 lo = 0, hi = ~0ull;
    while (lo < hi) {
        u64 span = hi - lo;
        u64 mid = lo + (span >> 1) + (span & 1);   // upper mid
        int c = 0;
        #pragma unroll
        for (int m = 0; m < 16; ++m) c += (int)(v[m] >= mid);
        #pragma unroll
        for (int off = 1; off < 64; off <<= 1) c += __shfl_xor(c, off);
        if (c >= KKEEP) lo = mid; else hi = mid - 1;   // uniform across lanes
    }

    int i = r & 1023;              // diagonal index within this head's MxM
    int* orow = out + ((size_t)r << 10);
    #pragma unroll
    for (int m = 0; m < 16; ++m)
        orow[l + m * 64] = (v[m] >= lo || (l + m * 64) == i) ? 1 : 0;
}

extern "C" void kernel_launch(void* const* d_in, const int* in_sizes, int n_in,
                              void* d_out, int out_size, void* d_ws, size_t ws_size,
                              hipStream_t stream) {
    const float* q = (const float*)d_in[0];
    const float* k = (const float*)d_in[1];
    int* out = (int*)d_out;
    char* ws = (char*)d_ws;

    float*  qc   = (float*)ws;                            //  4 MB
    float*  kc   = (float*)(ws + (4ull << 20));           //  4 MB
    double* A    = (double*)(ws + (8ull << 20));          // 64 MB
    double* neg  = (double*)(ws + (72ull << 20));         // 64 MB
    double* dgo  = (double*)(ws + (136ull << 20));        // 64 KB
    double* dgi  = dgo + 8192;                            // 64 KB
    double* pout = dgi + 8192;                            //  1 MB (8*16*16*64 doubles)
    double* pin  = pout + 131072;                         //  1 MB

    coarsen_kernel<<<16384, 256, 0, stream>>>(q, k, qc, kc);
    affinity_kernel<<<2048, 256, 0, stream>>>(qc, kc, A, pout, pin);
    deg_reduce_kernel<<<64, 256, 0, stream>>>(pout, pin, dgo, dgi);
    tri_kernel<<<dim3(8, 8, 8), 512, 0, stream>>>(A, dgo, dgi, neg);
    topk_mask_kernel<<<8192, 64, 0, stream>>>(neg, out);
}